// Round 2
// baseline (817.348 us; speedup 1.0000x reference)
//
#include <hip/hip_runtime.h>
#include <stdint.h>

// Problem constants (match reference)
#define USER_N 100000
#define ITEM_N 50000
#define TAG_N  20000
#define NN (USER_N + ITEM_N)   // 150000 interaction-graph nodes
#define MM (ITEM_N + TAG_N)    // 70000 tag-graph nodes
#define DD 64
#define NPART 8                // one row-partition per XCD (MI355X has 8 XCDs)

// ---------------------------------------------------------------------------
// JAX threefry2x32 (20 rounds), bit-exact (verified: R1 absmax 0.0).
// ---------------------------------------------------------------------------
__host__ __device__ __forceinline__ void tf2x32(uint32_t k0, uint32_t k1,
                                                uint32_t x0, uint32_t x1,
                                                uint32_t* o0, uint32_t* o1) {
  uint32_t ks2 = k0 ^ k1 ^ 0x1BD11BDAu;
#define ROTL32(v, d) (((v) << (d)) | ((v) >> (32 - (d))))
#define TF_RND(d) { x0 += x1; x1 = ROTL32(x1, d); x1 ^= x0; }
  x0 += k0; x1 += k1;
  TF_RND(13) TF_RND(15) TF_RND(26) TF_RND(6)
  x0 += k1;  x1 += ks2 + 1u;
  TF_RND(17) TF_RND(29) TF_RND(16) TF_RND(24)
  x0 += ks2; x1 += k0 + 2u;
  TF_RND(13) TF_RND(15) TF_RND(26) TF_RND(6)
  x0 += k0;  x1 += k1 + 3u;
  TF_RND(17) TF_RND(29) TF_RND(16) TF_RND(24)
  x0 += k1;  x1 += ks2 + 4u;
  TF_RND(13) TF_RND(15) TF_RND(26) TF_RND(6)
  x0 += ks2; x1 += k0 + 5u;
  *o0 = x0; *o1 = x1;
#undef TF_RND
#undef ROTL32
}

// keep-mask(e; key), bit-exact vs jax uniform+floor
__device__ __forceinline__ float drop_mask(uint32_t e, uint32_t k0, uint32_t k1) {
  uint32_t o0, o1;
  tf2x32(k0, k1, 0u, e, &o0, &o1);
  uint32_t bits = o0 ^ o1;
  float u = __uint_as_float((bits >> 9) | 0x3F800000u) - 1.0f;
  return floorf(u + 0.9f);
}

// bf16 helpers: RNE pack, exact shl unpack
__device__ __forceinline__ uint32_t f2bf(float f) {
  uint32_t u = __float_as_uint(f);
  return (u + 0x7fffu + ((u >> 16) & 1u)) >> 16;
}
__device__ __forceinline__ float bflo(uint32_t u) { return __uint_as_float(u << 16); }
__device__ __forceinline__ float bfhi(uint32_t u) { return __uint_as_float(u & 0xffff0000u); }

// ---------------------------------------------------------------------------
// CSR build (R9 structure): histpack -> hierarchical scan -> XCD-partitioned
// scatter (R9: WRITE_SIZE 125 MB -> partitioned rows keep each ~2 MB rec
// region in ONE XCD's L2 so lines coalesce before writeback).
// ---------------------------------------------------------------------------

// Coalesced pass: histogram atomic + threefry drop masks for BOTH layers,
// packed 2x bf16 into pk[e] (full lane utilization; pk write is coalesced).
__global__ void histpack_kernel(const int* __restrict__ rows, const float* __restrict__ vals,
                                int* __restrict__ cnt, uint32_t* __restrict__ pk, int nE,
                                uint32_t ka0, uint32_t ka1, uint32_t kb0, uint32_t kb1) {
  int e = blockIdx.x * blockDim.x + threadIdx.x;
  if (e >= nE) return;
  atomicAdd(&cnt[rows[e]], 1);
  const float SC = (float)(1.0 / 0.9);
  float v  = vals[e];
  float v0 = v * drop_mask((uint32_t)e, ka0, ka1) * SC;
  float v1 = v * drop_mask((uint32_t)e, kb0, kb1) * SC;
  pk[e] = f2bf(v0) | (f2bf(v1) << 16);   // dropped -> exact 0 bits
}

__global__ void scan1_kernel(const int* __restrict__ cnt, int* __restrict__ rp,
                             int* __restrict__ bsum, int n) {
  __shared__ int s[256];
  int t = threadIdx.x;
  int base = blockIdx.x * 1024 + t * 4;
  int c0 = (base + 0 < n) ? cnt[base + 0] : 0;
  int c1 = (base + 1 < n) ? cnt[base + 1] : 0;
  int c2 = (base + 2 < n) ? cnt[base + 2] : 0;
  int c3 = (base + 3 < n) ? cnt[base + 3] : 0;
  int tsum = c0 + c1 + c2 + c3;
  s[t] = tsum;
  __syncthreads();
  for (int off = 1; off < 256; off <<= 1) {
    int v = (t >= off) ? s[t - off] : 0;
    __syncthreads();
    s[t] += v;
    __syncthreads();
  }
  int excl = s[t] - tsum;
  if (base + 0 < n) rp[base + 0] = excl;
  if (base + 1 < n) rp[base + 1] = excl + c0;
  if (base + 2 < n) rp[base + 2] = excl + c0 + c1;
  if (base + 3 < n) rp[base + 3] = excl + c0 + c1 + c2;
  if (t == 255) bsum[blockIdx.x] = s[255];
}

__global__ void scan2_kernel(int* __restrict__ bsum, int B) {
  __shared__ int s[256];
  int t = threadIdx.x;
  int v = (t < B) ? bsum[t] : 0;
  s[t] = v;
  __syncthreads();
  for (int off = 1; off < 256; off <<= 1) {
    int x = (t >= off) ? s[t - off] : 0;
    __syncthreads();
    s[t] += x;
    __syncthreads();
  }
  if (t < B) bsum[t] = s[t] - v;
}

__global__ void scan3_kernel(int* __restrict__ rp, const int* __restrict__ bsum,
                             int* __restrict__ cursor, int n, int nE) {
  int i = blockIdx.x * blockDim.x + threadIdx.x;
  if (i < n) {
    int v = rp[i] + bsum[i >> 10];
    rp[i] = v;
    cursor[i] = v;
  }
  if (i == 0) rp[n] = nE;
}

// XCD-partitioned scatter: block (p, slice) scans edge slice, scatters only
// edges whose row falls in partition p's contiguous row range (p = blk%8 ->
// XCD p under round-robin dispatch; correctness independent of mapping).
__global__ void scatter_part_kernel(const int* __restrict__ rows, const int* __restrict__ cols,
                                    const uint32_t* __restrict__ pk,
                                    int* __restrict__ cursor, int2* __restrict__ rec,
                                    int nE, int nRows, int nSlices) {
  int p     = blockIdx.x & (NPART - 1);
  int slice = blockIdx.x >> 3;
  int lo = (int)((long long)p * nRows / NPART);
  int hi = (int)((long long)(p + 1) * nRows / NPART);
  int per = (nE + nSlices - 1) / nSlices;
  int e0 = slice * per;
  int e1 = e0 + per; if (e1 > nE) e1 = nE;
  for (int e = e0 + (int)threadIdx.x; e < e1; e += (int)blockDim.x) {
    int r = __builtin_nontemporal_load(&rows[e]);
    if (r >= lo && r < hi) {
      int      c = __builtin_nontemporal_load(&cols[e]);
      uint32_t w = __builtin_nontemporal_load(&pk[e]);
      int pos = atomicAdd(&cursor[r], 1);
      rec[pos] = make_int2(c, (int)w);
    }
  }
}

// ---------------------------------------------------------------------------
// Gather SpMM core, SUBGROUP-PER-ROW (R10). R9's counters: mega gather 115us,
// VALU 60%, HBM 28% -> latency/issue bound. Per-row cost was dominated by the
// cross-subgroup butterfly reduce (~100 instr/row vs ~50 instr of dot-product
// work at 13.3 edges/row) and the shfl->load serial chain. New scheme: each
// 8-lane subgroup owns ONE row (8 rows/wave): all 8 lanes load the same
// rec[i] (HW same-address broadcast, sequential addresses -> prefetchable,
// 4-way unrolled independent chains), each lane loads its own 16B feature
// chunk (128 B/edge contiguous per subgroup). NO shuffles, NO reduce, all
// lanes active at the write. Divergent per-subgroup trip counts are safe:
// no cross-lane ops remain (R3's wave-uniform constraint was shfl-only).
// Single src base: workspace laid out so [lat items][tag rows] contiguous.
// ---------------------------------------------------------------------------
template <int VS>
__device__ __forceinline__ void gather_sub(int s0, int s1, const int2* __restrict__ rec,
                                           const ushort* __restrict__ src,
                                           int fl, float4& A0, float4& A1) {
  float4 a0 = make_float4(0.f, 0.f, 0.f, 0.f);
  float4 a1 = make_float4(0.f, 0.f, 0.f, 0.f);
#define GBODY(ii) { \
    int2 m = rec[ii]; \
    uint32_t w = (uint32_t)m.y; \
    float v = VS ? bfhi(w) : bflo(w); \
    if (v != 0.0f) { \
      uint4 q = ((const uint4*)(src + (size_t)m.x * DD))[fl]; \
      a0.x += v * bflo(q.x); a0.y += v * bfhi(q.x); \
      a0.z += v * bflo(q.y); a0.w += v * bfhi(q.y); \
      a1.x += v * bflo(q.z); a1.y += v * bfhi(q.z); \
      a1.z += v * bflo(q.w); a1.w += v * bfhi(q.w); \
    } }
  int i = s0;
  for (; i + 4 <= s1; i += 4) { GBODY(i) GBODY(i + 1) GBODY(i + 2) GBODY(i + 3) }
  for (; i < s1; ++i) { GBODY(i) }
#undef GBODY
  A0 = a0; A1 = a1;
}

__device__ __forceinline__ float4 lk4(float4 x) {
  x.x = x.x >= 0.0f ? x.x : 0.5f * x.x;
  x.y = x.y >= 0.0f ? x.y : 0.5f * x.y;
  x.z = x.z >= 0.0f ? x.z : 0.5f * x.z;
  x.w = x.w >= 0.0f ? x.w : 0.5f * x.w;
  return x;
}

__device__ __forceinline__ uint4 pack8(float4 a, float4 b) {
  uint4 p;
  p.x = f2bf(a.x) | (f2bf(a.y) << 16);
  p.y = f2bf(a.z) | (f2bf(a.w) << 16);
  p.z = f2bf(b.x) | (f2bf(b.y) << 16);
  p.w = f2bf(b.z) | (f2bf(b.w) << 16);
  return p;
}

// Tag-node rows only (rr in [0,TAG_N)): out(bf16) = leaky(tag-spmm row ITEM_N+rr)
// src = contiguous [item rows of lat][tag source rows]
__global__ void gather_tagrows_kernel(const int* __restrict__ rp, const int2* __restrict__ rec,
                                      const ushort* __restrict__ src,
                                      ushort* __restrict__ out) {
  int rr = (blockIdx.x * blockDim.x + threadIdx.x) >> 3;
  if (rr >= TAG_N) return;
  int fl = threadIdx.x & 7;
  int r = rr + ITEM_N;
  float4 a0, a1;
  gather_sub<0>(rp[r], rp[r + 1], rec, src, fl, a0, a1);
  ((uint4*)(out + (size_t)rr * DD))[fl] = pack8(lk4(a0), lk4(a1));
}

// Mega gather over NN rows; tag gather for item rows fused inline.
// o = leaky(adj) + (r<USER ? leaky(soc) : leaky(tag_row))
// Tag source region = lat + USER_N*DD is CONTIGUOUS [items][tags] by layout.
// FINAL=false (layer 0): latOut(bf16) = o
// FINAL=true  (layer 1): acc(f32) += f32(lat[row]) + o   (lat = lat1 bf16)
template <int VS, bool FINAL>
__global__ void gather_mega_kernel(
    const int* __restrict__ arp, const int2* __restrict__ arec,
    const int* __restrict__ srp, const int2* __restrict__ srec,
    const int* __restrict__ trp, const int2* __restrict__ trec,
    const ushort* __restrict__ lat,   // NN x 64 bf16 (tag rows follow it)
    ushort* __restrict__ latOut, float* __restrict__ acc) {
  int r = (blockIdx.x * blockDim.x + threadIdx.x) >> 3;
  if (r >= NN) return;
  int fl = threadIdx.x & 7;
  float4 t0, t1, b0, b1;
  gather_sub<VS>(arp[r], arp[r + 1], arec, lat, fl, t0, t1);
  if (r < USER_N) {
    gather_sub<VS>(srp[r], srp[r + 1], srec, lat, fl, b0, b1);
  } else {
    int tr = r - USER_N;
    gather_sub<VS>(trp[tr], trp[tr + 1], trec, lat + (size_t)USER_N * DD, fl, b0, b1);
  }
  t0 = lk4(t0); t1 = lk4(t1); b0 = lk4(b0); b1 = lk4(b1);
  float4 o0 = make_float4(t0.x + b0.x, t0.y + b0.y, t0.z + b0.z, t0.w + b0.w);
  float4 o1 = make_float4(t1.x + b1.x, t1.y + b1.y, t1.z + b1.z, t1.w + b1.w);
  if (FINAL) {
    uint4 l = ((const uint4*)(lat + (size_t)r * DD))[fl];
    float4* ap = (float4*)(acc + (size_t)r * DD);
    float4 v0 = ap[fl * 2], v1 = ap[fl * 2 + 1];
    v0.x += bflo(l.x) + o0.x; v0.y += bfhi(l.x) + o0.y;
    v0.z += bflo(l.y) + o0.z; v0.w += bfhi(l.y) + o0.w;
    v1.x += bflo(l.z) + o1.x; v1.y += bfhi(l.z) + o1.y;
    v1.z += bflo(l.w) + o1.z; v1.w += bfhi(l.w) + o1.w;
    ap[fl * 2] = v0; ap[fl * 2 + 1] = v1;
  } else {
    ((uint4*)(latOut + (size_t)r * DD))[fl] = pack8(o0, o1);
  }
}

// acc(f32) = lat0 = concat(u, i); lat0bf = bf16(lat0); tEmbf = bf16(tEmbeds)
__global__ void init_kernel(const float4* __restrict__ u, const float4* __restrict__ it,
                            const float4* __restrict__ tE,
                            float4* __restrict__ acc, ushort4* __restrict__ lat0bf,
                            ushort4* __restrict__ tEmbf) {
  int idx = blockIdx.x * blockDim.x + threadIdx.x;  // NN*16 + TAG_N*16 float4s
  const int uN = USER_N * 16, nN = NN * 16;
  if (idx < nN) {
    float4 v = (idx < uN) ? u[idx] : it[idx - uN];
    acc[idx] = v;
    ushort4 h;
    h.x = (ushort)f2bf(v.x); h.y = (ushort)f2bf(v.y);
    h.z = (ushort)f2bf(v.z); h.w = (ushort)f2bf(v.w);
    lat0bf[idx] = h;
  } else if (idx < nN + TAG_N * 16) {
    int j = idx - nN;
    float4 v = tE[j];
    ushort4 h;
    h.x = (ushort)f2bf(v.x); h.y = (ushort)f2bf(v.y);
    h.z = (ushort)f2bf(v.z); h.w = (ushort)f2bf(v.w);
    tEmbf[j] = h;
  }
}

extern "C" void kernel_launch(void* const* d_in, const int* in_sizes, int n_in,
                              void* d_out, int out_size, void* d_ws, size_t ws_size,
                              hipStream_t stream) {
  const float* uE    = (const float*)d_in[0];
  const float* iE    = (const float*)d_in[1];
  const float* tEm   = (const float*)d_in[2];
  const int*   adj_r = (const int*)d_in[3];
  const int*   adj_c = (const int*)d_in[4];
  const float* adj_v = (const float*)d_in[5];
  const int*   tag_r = (const int*)d_in[6];
  const int*   tag_c = (const int*)d_in[7];
  const float* tag_v = (const float*)d_in[8];
  const int*   soc_r = (const int*)d_in[9];
  const int*   soc_c = (const int*)d_in[10];
  const float* soc_v = (const float*)d_in[11];
  const int nAdj = in_sizes[5], nTag = in_sizes[8], nSoc = in_sizes[11];

  float* acc = (float*)d_out;

  // Workspace (~86 MB). Layout makes BOTH tag-gather source regions
  // contiguous: [lat0 items][tEmbf] and [lat1 items][tg1bf].
  ushort* lat0bf = (ushort*)d_ws;                  // NN*DD bf16
  ushort* tEmbf  = lat0bf + (size_t)NN * DD;       // TAG_N*DD (follows lat0!)
  ushort* lat1bf = tEmbf  + (size_t)TAG_N * DD;    // NN*DD
  ushort* tg1bf  = lat1bf + (size_t)NN * DD;       // TAG_N*DD (follows lat1!)
  int2* a_rec = (int2*)(tg1bf + (size_t)TAG_N * DD);  // nAdj {col, bf16v0|bf16v1}
  int2* t_rec = a_rec + nAdj;                      // nTag
  int2* s_rec = t_rec + nTag;                      // nSoc
  int* ip    = (int*)(s_rec + nSoc);
  int* a_rp  = ip;  ip += NN + 1;
  int* a_cur = ip;  ip += NN;
  int* t_rp  = ip;  ip += MM + 1;
  int* t_cur = ip;  ip += MM;
  int* s_rp  = ip;  ip += USER_N + 1;
  int* s_cur = ip;  ip += USER_N;
  int* bsum  = ip;  ip += 256;
  // shared packed-value side array (reused per graph, sequential builds)
  int nPkMax = nAdj > nTag ? nAdj : nTag;
  if (nSoc > nPkMax) nPkMax = nSoc;
  uint32_t* pkbuf = (uint32_t*)ip;  ip += nPkMax;

  // fold_in(key(42), j) for j=0..5 (host-side, deterministic)
  uint32_t kk[6][2];
  for (uint32_t j = 0; j < 6; ++j) tf2x32(0u, 42u, 0u, j, &kk[j][0], &kk[j][1]);

  const int thr = 256;
#define CDIV(a, b) (((a) + (b) - 1) / (b))

  // ---- CSR build (once per call; records carry both layers' values) ----
  struct G { const int* rows; const int* cols; const float* vals; int n; int nE;
             int* rp; int* cur; int2* rec; int k0; int k1; };
  G gs[3] = {
      {adj_r, adj_c, adj_v, NN,     nAdj, a_rp, a_cur, a_rec, 0, 3},
      {tag_r, tag_c, tag_v, MM,     nTag, t_rp, t_cur, t_rec, 1, 4},
      {soc_r, soc_c, soc_v, USER_N, nSoc, s_rp, s_cur, s_rec, 2, 5},
  };
  for (int g = 0; g < 3; ++g) {
    hipMemsetAsync(gs[g].cur, 0, (size_t)gs[g].n * sizeof(int), stream);
    histpack_kernel<<<CDIV(gs[g].nE, thr), thr, 0, stream>>>(
        gs[g].rows, gs[g].vals, gs[g].cur, pkbuf, gs[g].nE,
        kk[gs[g].k0][0], kk[gs[g].k0][1], kk[gs[g].k1][0], kk[gs[g].k1][1]);
    int B = CDIV(gs[g].n, 1024);
    scan1_kernel<<<B, 256, 0, stream>>>(gs[g].cur, gs[g].rp, bsum, gs[g].n);
    scan2_kernel<<<1, 256, 0, stream>>>(bsum, B);
    scan3_kernel<<<CDIV(gs[g].n, thr), thr, 0, stream>>>(gs[g].rp, bsum, gs[g].cur, gs[g].n, gs[g].nE);
    int nSlices = CDIV(gs[g].nE, 4096);
    scatter_part_kernel<<<nSlices * NPART, thr, 0, stream>>>(
        gs[g].rows, gs[g].cols, pkbuf, gs[g].cur, gs[g].rec, gs[g].nE, gs[g].n, nSlices);
  }

  // ---- init: acc = lat0 (f32); lat0bf, tEmbf (bf16 gather sources) ----
  init_kernel<<<CDIV((NN + TAG_N) * 16, thr), thr, 0, stream>>>(
      (const float4*)uE, (const float4*)iE, (const float4*)tEm,
      (float4*)acc, (ushort4*)lat0bf, (ushort4*)tEmbf);

  // ---- layer 0 ----
  // tg1 = leaky(tag-spmm) for tag-node rows (layer-1 tag sources)
  gather_tagrows_kernel<<<CDIV(TAG_N * 8, thr), thr, 0, stream>>>(
      t_rp, t_rec, lat0bf + (size_t)USER_N * DD, tg1bf);

  // lat1 = combine(leaky(adj), leaky(soc) | leaky(tag item rows)); acc untouched
  gather_mega_kernel<0, false><<<CDIV(NN * 8, thr), thr, 0, stream>>>(
      a_rp, a_rec, s_rp, s_rec, t_rp, t_rec, lat0bf, lat1bf, nullptr);

  // ---- layer 1 ----
  // acc += lat1 + combine(leaky(adj), leaky(soc) | leaky(tag item rows))
  gather_mega_kernel<1, true><<<CDIV(NN * 8, thr), thr, 0, stream>>>(
      a_rp, a_rec, s_rp, s_rec, t_rp, t_rec, lat1bf, nullptr, acc);
#undef CDIV
}

// Round 3
// 717.619 us; speedup vs baseline: 1.1390x; 1.1390x over previous
//
#include <hip/hip_runtime.h>
#include <stdint.h>

// Problem constants (match reference)
#define USER_N 100000
#define ITEM_N 50000
#define TAG_N  20000
#define NN (USER_N + ITEM_N)   // 150000 interaction-graph nodes
#define MM (ITEM_N + TAG_N)    // 70000 tag-graph nodes
#define DD 64
#define NPART 8                // one row-partition per XCD (MI355X has 8 XCDs)

// ---------------------------------------------------------------------------
// JAX threefry2x32 (20 rounds), bit-exact (verified: R1 absmax 0.0).
// ---------------------------------------------------------------------------
__host__ __device__ __forceinline__ void tf2x32(uint32_t k0, uint32_t k1,
                                                uint32_t x0, uint32_t x1,
                                                uint32_t* o0, uint32_t* o1) {
  uint32_t ks2 = k0 ^ k1 ^ 0x1BD11BDAu;
#define ROTL32(v, d) (((v) << (d)) | ((v) >> (32 - (d))))
#define TF_RND(d) { x0 += x1; x1 = ROTL32(x1, d); x1 ^= x0; }
  x0 += k0; x1 += k1;
  TF_RND(13) TF_RND(15) TF_RND(26) TF_RND(6)
  x0 += k1;  x1 += ks2 + 1u;
  TF_RND(17) TF_RND(29) TF_RND(16) TF_RND(24)
  x0 += ks2; x1 += k0 + 2u;
  TF_RND(13) TF_RND(15) TF_RND(26) TF_RND(6)
  x0 += k0;  x1 += k1 + 3u;
  TF_RND(17) TF_RND(29) TF_RND(16) TF_RND(24)
  x0 += k1;  x1 += ks2 + 4u;
  TF_RND(13) TF_RND(15) TF_RND(26) TF_RND(6)
  x0 += ks2; x1 += k0 + 5u;
  *o0 = x0; *o1 = x1;
#undef TF_RND
#undef ROTL32
}

// keep-mask(e; key), bit-exact vs jax uniform+floor
__device__ __forceinline__ float drop_mask(uint32_t e, uint32_t k0, uint32_t k1) {
  uint32_t o0, o1;
  tf2x32(k0, k1, 0u, e, &o0, &o1);
  uint32_t bits = o0 ^ o1;
  float u = __uint_as_float((bits >> 9) | 0x3F800000u) - 1.0f;
  return floorf(u + 0.9f);
}

// bf16 helpers: RNE pack, exact shl unpack
__device__ __forceinline__ uint32_t f2bf(float f) {
  uint32_t u = __float_as_uint(f);
  return (u + 0x7fffu + ((u >> 16) & 1u)) >> 16;
}
__device__ __forceinline__ float bflo(uint32_t u) { return __uint_as_float(u << 16); }
__device__ __forceinline__ float bfhi(uint32_t u) { return __uint_as_float(u & 0xffff0000u); }

// ---------------------------------------------------------------------------
// CSR build (R9 structure): histpack -> hierarchical scan -> XCD-partitioned
// scatter (R9: WRITE_SIZE 125 MB -> partitioned rows keep each ~2 MB rec
// region in ONE XCD's L2 so lines coalesce before writeback).
// ---------------------------------------------------------------------------

// Coalesced pass: histogram atomic + threefry drop masks for BOTH layers,
// packed 2x bf16 into pk[e] (full lane utilization; pk write is coalesced).
__global__ void histpack_kernel(const int* __restrict__ rows, const float* __restrict__ vals,
                                int* __restrict__ cnt, uint32_t* __restrict__ pk, int nE,
                                uint32_t ka0, uint32_t ka1, uint32_t kb0, uint32_t kb1) {
  int e = blockIdx.x * blockDim.x + threadIdx.x;
  if (e >= nE) return;
  atomicAdd(&cnt[rows[e]], 1);
  const float SC = (float)(1.0 / 0.9);
  float v  = vals[e];
  float v0 = v * drop_mask((uint32_t)e, ka0, ka1) * SC;
  float v1 = v * drop_mask((uint32_t)e, kb0, kb1) * SC;
  pk[e] = f2bf(v0) | (f2bf(v1) << 16);   // dropped -> exact 0 bits
}

__global__ void scan1_kernel(const int* __restrict__ cnt, int* __restrict__ rp,
                             int* __restrict__ bsum, int n) {
  __shared__ int s[256];
  int t = threadIdx.x;
  int base = blockIdx.x * 1024 + t * 4;
  int c0 = (base + 0 < n) ? cnt[base + 0] : 0;
  int c1 = (base + 1 < n) ? cnt[base + 1] : 0;
  int c2 = (base + 2 < n) ? cnt[base + 2] : 0;
  int c3 = (base + 3 < n) ? cnt[base + 3] : 0;
  int tsum = c0 + c1 + c2 + c3;
  s[t] = tsum;
  __syncthreads();
  for (int off = 1; off < 256; off <<= 1) {
    int v = (t >= off) ? s[t - off] : 0;
    __syncthreads();
    s[t] += v;
    __syncthreads();
  }
  int excl = s[t] - tsum;
  if (base + 0 < n) rp[base + 0] = excl;
  if (base + 1 < n) rp[base + 1] = excl + c0;
  if (base + 2 < n) rp[base + 2] = excl + c0 + c1;
  if (base + 3 < n) rp[base + 3] = excl + c0 + c1 + c2;
  if (t == 255) bsum[blockIdx.x] = s[255];
}

__global__ void scan2_kernel(int* __restrict__ bsum, int B) {
  __shared__ int s[256];
  int t = threadIdx.x;
  int v = (t < B) ? bsum[t] : 0;
  s[t] = v;
  __syncthreads();
  for (int off = 1; off < 256; off <<= 1) {
    int x = (t >= off) ? s[t - off] : 0;
    __syncthreads();
    s[t] += x;
    __syncthreads();
  }
  if (t < B) bsum[t] = s[t] - v;
}

__global__ void scan3_kernel(int* __restrict__ rp, const int* __restrict__ bsum,
                             int* __restrict__ cursor, int n, int nE) {
  int i = blockIdx.x * blockDim.x + threadIdx.x;
  if (i < n) {
    int v = rp[i] + bsum[i >> 10];
    rp[i] = v;
    cursor[i] = v;
  }
  if (i == 0) rp[n] = nE;
}

// XCD-partitioned scatter: block (p, slice) scans edge slice, scatters only
// edges whose row falls in partition p's contiguous row range (p = blk%8 ->
// XCD p under round-robin dispatch; correctness independent of mapping).
// Record: {col*DD (pre-scaled ushort offset), bf16v0|bf16v1<<16}.
__global__ void scatter_part_kernel(const int* __restrict__ rows, const int* __restrict__ cols,
                                    const uint32_t* __restrict__ pk,
                                    int* __restrict__ cursor, int2* __restrict__ rec,
                                    int nE, int nRows, int nSlices) {
  int p     = blockIdx.x & (NPART - 1);
  int slice = blockIdx.x >> 3;
  int lo = (int)((long long)p * nRows / NPART);
  int hi = (int)((long long)(p + 1) * nRows / NPART);
  int per = (nE + nSlices - 1) / nSlices;
  int e0 = slice * per;
  int e1 = e0 + per; if (e1 > nE) e1 = nE;
  for (int e = e0 + (int)threadIdx.x; e < e1; e += (int)blockDim.x) {
    int r = __builtin_nontemporal_load(&rows[e]);
    if (r >= lo && r < hi) {
      int      c = __builtin_nontemporal_load(&cols[e]);
      uint32_t w = __builtin_nontemporal_load(&pk[e]);
      int pos = atomicAdd(&cursor[r], 1);
      rec[pos] = make_int2(c * DD, (int)w);
    }
  }
}

// ---------------------------------------------------------------------------
// Gather SpMM core, BATCHED BRANCH-FREE subgroup-per-row (R11).
// R10 post-mortem: VALUBusy 19%, HBM 26%, occ 65% -> latency-bound, low MLP.
// The per-edge (v!=0) branch between rec load and feature load made each
// unrolled body a basic block: ~1-2 feature loads in flight. R11: per 8-edge
// batch, phase 1 loads 8 recs (nontemporal: rec streams once, don't evict
// the 19 MB feature table from L2), phase 2 issues all 8 feature loads
// back-to-back (NO branches; dropped edges contribute exact 0*x), phase 3
// accumulates into 2 interleaved accumulator sets (break FMA serial chain).
// Compiler emits progressive vmcnt waits -> ~8 feature loads (128 lines/wave)
// in flight. Divergent per-subgroup trip counts safe: no cross-lane ops.
// ---------------------------------------------------------------------------
#define FMA8(c0, c1, v, q) { \
    c0.x += v * bflo(q.x); c0.y += v * bfhi(q.x); \
    c0.z += v * bflo(q.y); c0.w += v * bfhi(q.y); \
    c1.x += v * bflo(q.z); c1.y += v * bfhi(q.z); \
    c1.z += v * bflo(q.w); c1.w += v * bfhi(q.w); }

template <int VS>
__device__ __forceinline__ void gather_sub(int s0, int s1, const int2* __restrict__ rec,
                                           const ushort* __restrict__ src,
                                           int fl, float4& A0, float4& A1) {
  float4 a0 = make_float4(0.f, 0.f, 0.f, 0.f);
  float4 a1 = make_float4(0.f, 0.f, 0.f, 0.f);
  float4 b0 = make_float4(0.f, 0.f, 0.f, 0.f);
  float4 b1 = make_float4(0.f, 0.f, 0.f, 0.f);
  const ushort* sl = src + fl * 8;   // this lane's 16 B slice base
  int i = s0;
  for (; i + 8 <= s1; i += 8) {
    long long r[8];
    uint4 q[8];
#pragma unroll
    for (int u = 0; u < 8; ++u)
      r[u] = __builtin_nontemporal_load((const long long*)(rec + i + u));
#pragma unroll
    for (int u = 0; u < 8; ++u)
      q[u] = *(const uint4*)(sl + (uint32_t)r[u]);
#pragma unroll
    for (int u = 0; u < 8; ++u) {
      uint32_t w = (uint32_t)((unsigned long long)r[u] >> 32);
      float v = VS ? bfhi(w) : bflo(w);
      if (u & 1) { FMA8(b0, b1, v, q[u]) } else { FMA8(a0, a1, v, q[u]) }
    }
  }
  if (i + 4 <= s1) {
    long long r[4];
    uint4 q[4];
#pragma unroll
    for (int u = 0; u < 4; ++u)
      r[u] = __builtin_nontemporal_load((const long long*)(rec + i + u));
#pragma unroll
    for (int u = 0; u < 4; ++u)
      q[u] = *(const uint4*)(sl + (uint32_t)r[u]);
#pragma unroll
    for (int u = 0; u < 4; ++u) {
      uint32_t w = (uint32_t)((unsigned long long)r[u] >> 32);
      float v = VS ? bfhi(w) : bflo(w);
      if (u & 1) { FMA8(b0, b1, v, q[u]) } else { FMA8(a0, a1, v, q[u]) }
    }
    i += 4;
  }
  for (; i < s1; ++i) {
    long long rr = __builtin_nontemporal_load((const long long*)(rec + i));
    uint4 q = *(const uint4*)(sl + (uint32_t)rr);
    uint32_t w = (uint32_t)((unsigned long long)rr >> 32);
    float v = VS ? bfhi(w) : bflo(w);
    FMA8(a0, a1, v, q)
  }
  A0 = make_float4(a0.x + b0.x, a0.y + b0.y, a0.z + b0.z, a0.w + b0.w);
  A1 = make_float4(a1.x + b1.x, a1.y + b1.y, a1.z + b1.z, a1.w + b1.w);
}

__device__ __forceinline__ float4 lk4(float4 x) {
  x.x = x.x >= 0.0f ? x.x : 0.5f * x.x;
  x.y = x.y >= 0.0f ? x.y : 0.5f * x.y;
  x.z = x.z >= 0.0f ? x.z : 0.5f * x.z;
  x.w = x.w >= 0.0f ? x.w : 0.5f * x.w;
  return x;
}

__device__ __forceinline__ uint4 pack8(float4 a, float4 b) {
  uint4 p;
  p.x = f2bf(a.x) | (f2bf(a.y) << 16);
  p.y = f2bf(a.z) | (f2bf(a.w) << 16);
  p.z = f2bf(b.x) | (f2bf(b.y) << 16);
  p.w = f2bf(b.z) | (f2bf(b.w) << 16);
  return p;
}

// Mega gather; grid covers NN rows (+TAG_N virtual rows when WITHTAG).
// r < NN:  o = leaky(adj) + (r<USER ? leaky(soc) : leaky(tag item row))
//   FINAL=false: latOut(bf16) = o ; FINAL=true: acc(f32) += f32(lat[r]) + o
// r >= NN (WITHTAG only): rr = r-NN; tgOut[rr] = leaky(tag row ITEM_N+rr)
// Tag source region = lat + USER_N*DD is CONTIGUOUS [items][tags] by layout.
template <int VS, bool FINAL, bool WITHTAG>
__global__ void gather_mega_kernel(
    const int* __restrict__ arp, const int2* __restrict__ arec,
    const int* __restrict__ srp, const int2* __restrict__ srec,
    const int* __restrict__ trp, const int2* __restrict__ trec,
    const ushort* __restrict__ lat,   // NN x 64 bf16 (tag rows follow it)
    ushort* __restrict__ latOut, ushort* __restrict__ tgOut,
    float* __restrict__ acc) {
  int r = (blockIdx.x * blockDim.x + threadIdx.x) >> 3;
  int fl = threadIdx.x & 7;
  if (WITHTAG && r >= NN) {
    int rr = r - NN;
    if (rr >= TAG_N) return;
    int tr = rr + ITEM_N;
    float4 a0, a1;
    gather_sub<VS>(trp[tr], trp[tr + 1], trec, lat + (size_t)USER_N * DD, fl, a0, a1);
    ((uint4*)(tgOut + (size_t)rr * DD))[fl] = pack8(lk4(a0), lk4(a1));
    return;
  }
  if (r >= NN) return;
  float4 t0, t1, b0, b1;
  gather_sub<VS>(arp[r], arp[r + 1], arec, lat, fl, t0, t1);
  if (r < USER_N) {
    gather_sub<VS>(srp[r], srp[r + 1], srec, lat, fl, b0, b1);
  } else {
    int tr = r - USER_N;
    gather_sub<VS>(trp[tr], trp[tr + 1], trec, lat + (size_t)USER_N * DD, fl, b0, b1);
  }
  t0 = lk4(t0); t1 = lk4(t1); b0 = lk4(b0); b1 = lk4(b1);
  float4 o0 = make_float4(t0.x + b0.x, t0.y + b0.y, t0.z + b0.z, t0.w + b0.w);
  float4 o1 = make_float4(t1.x + b1.x, t1.y + b1.y, t1.z + b1.z, t1.w + b1.w);
  if (FINAL) {
    uint4 l = ((const uint4*)(lat + (size_t)r * DD))[fl];
    float4* ap = (float4*)(acc + (size_t)r * DD);
    float4 v0 = ap[fl * 2], v1 = ap[fl * 2 + 1];
    v0.x += bflo(l.x) + o0.x; v0.y += bfhi(l.x) + o0.y;
    v0.z += bflo(l.y) + o0.z; v0.w += bfhi(l.y) + o0.w;
    v1.x += bflo(l.z) + o1.x; v1.y += bfhi(l.z) + o1.y;
    v1.z += bflo(l.w) + o1.z; v1.w += bfhi(l.w) + o1.w;
    ap[fl * 2] = v0; ap[fl * 2 + 1] = v1;
  } else {
    ((uint4*)(latOut + (size_t)r * DD))[fl] = pack8(o0, o1);
  }
}

// acc(f32) = lat0 = concat(u, i); lat0bf = bf16(lat0); tEmbf = bf16(tEmbeds)
__global__ void init_kernel(const float4* __restrict__ u, const float4* __restrict__ it,
                            const float4* __restrict__ tE,
                            float4* __restrict__ acc, ushort4* __restrict__ lat0bf,
                            ushort4* __restrict__ tEmbf) {
  int idx = blockIdx.x * blockDim.x + threadIdx.x;  // NN*16 + TAG_N*16 float4s
  const int uN = USER_N * 16, nN = NN * 16;
  if (idx < nN) {
    float4 v = (idx < uN) ? u[idx] : it[idx - uN];
    acc[idx] = v;
    ushort4 h;
    h.x = (ushort)f2bf(v.x); h.y = (ushort)f2bf(v.y);
    h.z = (ushort)f2bf(v.z); h.w = (ushort)f2bf(v.w);
    lat0bf[idx] = h;
  } else if (idx < nN + TAG_N * 16) {
    int j = idx - nN;
    float4 v = tE[j];
    ushort4 h;
    h.x = (ushort)f2bf(v.x); h.y = (ushort)f2bf(v.y);
    h.z = (ushort)f2bf(v.z); h.w = (ushort)f2bf(v.w);
    tEmbf[j] = h;
  }
}

extern "C" void kernel_launch(void* const* d_in, const int* in_sizes, int n_in,
                              void* d_out, int out_size, void* d_ws, size_t ws_size,
                              hipStream_t stream) {
  const float* uE    = (const float*)d_in[0];
  const float* iE    = (const float*)d_in[1];
  const float* tEm   = (const float*)d_in[2];
  const int*   adj_r = (const int*)d_in[3];
  const int*   adj_c = (const int*)d_in[4];
  const float* adj_v = (const float*)d_in[5];
  const int*   tag_r = (const int*)d_in[6];
  const int*   tag_c = (const int*)d_in[7];
  const float* tag_v = (const float*)d_in[8];
  const int*   soc_r = (const int*)d_in[9];
  const int*   soc_c = (const int*)d_in[10];
  const float* soc_v = (const float*)d_in[11];
  const int nAdj = in_sizes[5], nTag = in_sizes[8], nSoc = in_sizes[11];

  float* acc = (float*)d_out;

  // Workspace (~86 MB). Layout makes BOTH tag-gather source regions
  // contiguous: [lat0 items][tEmbf] and [lat1 items][tg1bf].
  ushort* lat0bf = (ushort*)d_ws;                  // NN*DD bf16
  ushort* tEmbf  = lat0bf + (size_t)NN * DD;       // TAG_N*DD (follows lat0!)
  ushort* lat1bf = tEmbf  + (size_t)TAG_N * DD;    // NN*DD
  ushort* tg1bf  = lat1bf + (size_t)NN * DD;       // TAG_N*DD (follows lat1!)
  int2* a_rec = (int2*)(tg1bf + (size_t)TAG_N * DD);  // nAdj {col*DD, bf16v0|bf16v1}
  int2* t_rec = a_rec + nAdj;                      // nTag
  int2* s_rec = t_rec + nTag;                      // nSoc
  int* ip    = (int*)(s_rec + nSoc);
  int* a_rp  = ip;  ip += NN + 1;
  int* a_cur = ip;  ip += NN;
  int* t_rp  = ip;  ip += MM + 1;
  int* t_cur = ip;  ip += MM;
  int* s_rp  = ip;  ip += USER_N + 1;
  int* s_cur = ip;  ip += USER_N;
  int* bsum  = ip;  ip += 256;
  // shared packed-value side array (reused per graph, sequential builds)
  int nPkMax = nAdj > nTag ? nAdj : nTag;
  if (nSoc > nPkMax) nPkMax = nSoc;
  uint32_t* pkbuf = (uint32_t*)ip;  ip += nPkMax;

  // fold_in(key(42), j) for j=0..5 (host-side, deterministic)
  uint32_t kk[6][2];
  for (uint32_t j = 0; j < 6; ++j) tf2x32(0u, 42u, 0u, j, &kk[j][0], &kk[j][1]);

  const int thr = 256;
#define CDIV(a, b) (((a) + (b) - 1) / (b))

  // ---- CSR build (once per call; records carry both layers' values) ----
  struct G { const int* rows; const int* cols; const float* vals; int n; int nE;
             int* rp; int* cur; int2* rec; int k0; int k1; };
  G gs[3] = {
      {adj_r, adj_c, adj_v, NN,     nAdj, a_rp, a_cur, a_rec, 0, 3},
      {tag_r, tag_c, tag_v, MM,     nTag, t_rp, t_cur, t_rec, 1, 4},
      {soc_r, soc_c, soc_v, USER_N, nSoc, s_rp, s_cur, s_rec, 2, 5},
  };
  for (int g = 0; g < 3; ++g) {
    hipMemsetAsync(gs[g].cur, 0, (size_t)gs[g].n * sizeof(int), stream);
    histpack_kernel<<<CDIV(gs[g].nE, thr), thr, 0, stream>>>(
        gs[g].rows, gs[g].vals, gs[g].cur, pkbuf, gs[g].nE,
        kk[gs[g].k0][0], kk[gs[g].k0][1], kk[gs[g].k1][0], kk[gs[g].k1][1]);
    int B = CDIV(gs[g].n, 1024);
    scan1_kernel<<<B, 256, 0, stream>>>(gs[g].cur, gs[g].rp, bsum, gs[g].n);
    scan2_kernel<<<1, 256, 0, stream>>>(bsum, B);
    scan3_kernel<<<CDIV(gs[g].n, thr), thr, 0, stream>>>(gs[g].rp, bsum, gs[g].cur, gs[g].n, gs[g].nE);
    int nSlices = CDIV(gs[g].nE, 4096);
    scatter_part_kernel<<<nSlices * NPART, thr, 0, stream>>>(
        gs[g].rows, gs[g].cols, pkbuf, gs[g].cur, gs[g].rec, gs[g].nE, gs[g].n, nSlices);
  }

  // ---- init: acc = lat0 (f32); lat0bf, tEmbf (bf16 gather sources) ----
  init_kernel<<<CDIV((NN + TAG_N) * 16, thr), thr, 0, stream>>>(
      (const float4*)uE, (const float4*)iE, (const float4*)tEm,
      (float4*)acc, (ushort4*)lat0bf, (ushort4*)tEmbf);

  // ---- layer 0 (tag-node rows fused into the same launch) ----
  // lat1 = combine(leaky(adj), leaky(soc) | leaky(tag item rows));
  // tg1 = leaky(tag-spmm tag rows) for layer-1 tag sources
  gather_mega_kernel<0, false, true><<<CDIV((NN + TAG_N) * 8, thr), thr, 0, stream>>>(
      a_rp, a_rec, s_rp, s_rec, t_rp, t_rec, lat0bf, lat1bf, tg1bf, nullptr);

  // ---- layer 1 ----
  // acc += lat1 + combine(leaky(adj), leaky(soc) | leaky(tag item rows))
  gather_mega_kernel<1, true, false><<<CDIV(NN * 8, thr), thr, 0, stream>>>(
      a_rp, a_rec, s_rp, s_rec, t_rp, t_rec, lat1bf, nullptr, nullptr, acc);
#undef CDIV
}